// Round 3
// baseline (748.909 us; speedup 1.0000x reference)
//
#include <hip/hip_runtime.h>
#include <hip/hip_bf16.h>
#include <stdint.h>

#define SEQ 2048
#define DIMSZ 4096
#define QKVN 6144   // 4096 Q + 1024 K + 1024 V

typedef __attribute__((ext_vector_type(8))) __bf16 bf16x8;
typedef __attribute__((ext_vector_type(4))) float f32x4;

// async global->LDS, 16B per lane; dest = wave-uniform base + lane*16
static __device__ __forceinline__ void gld_lds16(const void* g, void* l) {
  __builtin_amdgcn_global_load_lds(
      (__attribute__((address_space(1))) void*)(g),
      (__attribute__((address_space(3))) void*)(l), 16, 0, 0);
}

// ---------------- fp32 -> bf16 conversion (vectorized) ----------------
__global__ __launch_bounds__(256) void k_cvt(const float* __restrict__ in,
                                             __bf16* __restrict__ out, long n) {
  long i = (long)blockIdx.x * 256 + threadIdx.x;
  long stride = (long)gridDim.x * 256;
  for (long e = i * 8; e < n; e += stride * 8) {
    float4 v0 = *(const float4*)(in + e);
    float4 v1 = *(const float4*)(in + e + 4);
    bf16x8 o;
    o[0] = (__bf16)v0.x; o[1] = (__bf16)v0.y; o[2] = (__bf16)v0.z; o[3] = (__bf16)v0.w;
    o[4] = (__bf16)v1.x; o[5] = (__bf16)v1.y; o[6] = (__bf16)v1.z; o[7] = (__bf16)v1.w;
    *(bf16x8*)(out + e) = o;
  }
}

// ---------------- bf16 GEMM, C = A * B^T  (A: MxK, B: NxK, both K-contig) --
// 128x256 tile, BK=64, 8 waves (2x4), 96 KiB LDS double-buffer.
// T1: bijective XCD swizzle (nwg % 8 == 0 for both call sites).
// T2: 16B-chunk XOR swizzle (chunk ^= row&7), pre-swizzled global source,
//     same involution on the ds_read side -> conflict-free b128 reads.
// T3-minimum: prefetch tile j+1 issued at TOP of tile j's compute; single
//     vmcnt(0) drain per tile (inside __syncthreads) after a full tile of
//     MFMA has covered the HBM latency.
// T5: setprio(1) around each 16-MFMA cluster; phases split by s_barrier.
template <typename OutT>
__global__ __launch_bounds__(512) void k_gemm256(const __bf16* __restrict__ A,
                                                 const __bf16* __restrict__ B,
                                                 OutT* __restrict__ C,
                                                 int M, int N, int K) {
  __shared__ __bf16 As[2][128 * 64];  // 32 KiB
  __shared__ __bf16 Bs[2][256 * 64];  // 64 KiB
  const int nbn = N >> 8;
  const int nwg = (M >> 7) * nbn;
  const int orig = blockIdx.x;
  const int wg = (orig & 7) * (nwg >> 3) + (orig >> 3);  // XCD-contiguous chunks
  const int bm = wg / nbn, bn = wg % nbn;

  const int t = threadIdx.x;
  const int l = t & 63;
  const int w = t >> 6;        // 0..7
  const int wm = w >> 2;       // 0..1  (64-row half of the 128-row tile)
  const int wn = w & 3;        // 0..3  (64-col quarter of the 256-col tile)
  const int lr = l & 15, lg = l >> 4;
  const int sw = lr & 7;       // read-side chunk XOR

  const __bf16* Ab = A + (size_t)bm * 128 * K;
  const __bf16* Bb = B + (size_t)bn * 256 * K;

  // staging geometry: one issue = 512 thr x 16B = 64 rows x 64 cols
  const int srow = t >> 3;                       // row within issue
  const int scol = ((t & 7) ^ (srow & 7)) << 3;  // pre-swizzled source col (elems)
  const int ldst = (t & ~63) * 8;                // wave-uniform LDS elem base

  f32x4 acc[4][4] = {};

  const int ntiles = K >> 6;

  // prologue: stage tile 0 into buf 0
  {
#pragma unroll
    for (int i = 0; i < 2; ++i)
      gld_lds16(Ab + (size_t)(i * 64 + srow) * K + scol, &As[0][i * 4096 + ldst]);
#pragma unroll
    for (int i = 0; i < 4; ++i)
      gld_lds16(Bb + (size_t)(i * 64 + srow) * K + scol, &Bs[0][i * 4096 + ldst]);
  }
  __syncthreads();

  for (int j = 0; j < ntiles; ++j) {
    const int d = j & 1;
    // prefetch tile j+1 into the other buffer (its consumers finished last iter)
    if (j + 1 < ntiles) {
      const int kt = (j + 1) << 6;
#pragma unroll
      for (int i = 0; i < 2; ++i)
        gld_lds16(Ab + (size_t)(i * 64 + srow) * K + kt + scol, &As[d ^ 1][i * 4096 + ldst]);
#pragma unroll
      for (int i = 0; i < 4; ++i)
        gld_lds16(Bb + (size_t)(i * 64 + srow) * K + kt + scol, &Bs[d ^ 1][i * 4096 + ldst]);
    }

    // ---- phase 1: all mi, ni 0..1 ----
    bf16x8 a[4][2], b[2][2];
#pragma unroll
    for (int mi = 0; mi < 4; ++mi)
#pragma unroll
      for (int ks = 0; ks < 2; ++ks)
        a[mi][ks] = *(const bf16x8*)&As[d][(wm * 64 + mi * 16 + lr) * 64 + (((ks * 4 + lg) ^ sw) * 8)];
#pragma unroll
    for (int ni = 0; ni < 2; ++ni)
#pragma unroll
      for (int ks = 0; ks < 2; ++ks)
        b[ni][ks] = *(const bf16x8*)&Bs[d][(wn * 64 + ni * 16 + lr) * 64 + (((ks * 4 + lg) ^ sw) * 8)];
    __builtin_amdgcn_s_setprio(1);
#pragma unroll
    for (int mi = 0; mi < 4; ++mi)
#pragma unroll
      for (int ni = 0; ni < 2; ++ni)
#pragma unroll
        for (int ks = 0; ks < 2; ++ks)
          acc[mi][ni] = __builtin_amdgcn_mfma_f32_16x16x32_bf16(a[mi][ks], b[ni][ks], acc[mi][ni], 0, 0, 0);
    __builtin_amdgcn_s_setprio(0);
    __builtin_amdgcn_s_barrier();

    // ---- phase 2: all mi, ni 2..3 (A frags reused from registers) ----
#pragma unroll
    for (int ni = 0; ni < 2; ++ni)
#pragma unroll
      for (int ks = 0; ks < 2; ++ks)
        b[ni][ks] = *(const bf16x8*)&Bs[d][(wn * 64 + (ni + 2) * 16 + lr) * 64 + (((ks * 4 + lg) ^ sw) * 8)];
    __builtin_amdgcn_s_setprio(1);
#pragma unroll
    for (int mi = 0; mi < 4; ++mi)
#pragma unroll
      for (int ni = 0; ni < 2; ++ni)
#pragma unroll
        for (int ks = 0; ks < 2; ++ks)
          acc[mi][ni + 2] = __builtin_amdgcn_mfma_f32_16x16x32_bf16(a[mi][ks], b[ni][ks], acc[mi][ni + 2], 0, 0, 0);
    __builtin_amdgcn_s_setprio(0);

    // tile boundary: drains vmcnt(0) (prefetch had a full tile to land) + barrier
    __syncthreads();
  }

  const int row0 = bm * 128 + wm * 64;
  const int col0 = bn * 256 + wn * 64;
#pragma unroll
  for (int mi = 0; mi < 4; ++mi)
#pragma unroll
    for (int ni = 0; ni < 4; ++ni)
#pragma unroll
      for (int r = 0; r < 4; ++r)
        C[(size_t)(row0 + mi * 16 + lg * 4 + r) * N + (col0 + ni * 16 + lr)] =
            (OutT)acc[mi][ni][r];
}

// ---------------- fused RoPE + RMSNorm (in-place on Q and K regions) -------
__global__ __launch_bounds__(256) void k_rope_norm(__bf16* __restrict__ qkv,
                                                   const float* __restrict__ cosT,
                                                   const float* __restrict__ sinT) {
  const int task = blockIdx.x * 4 + (threadIdx.x >> 6);
  const int l = threadIdx.x & 63;
  const int m = task / 40;          // row in [0, 4096)
  const int h = task - m * 40;      // 0..31 = Q heads, 32..39 = K heads
  const int s = m & (SEQ - 1);
  const bool isQ = h < 32;
  const int col = isQ ? h * 128 : 4096 + (h - 32) * 128;
  __bf16* p = qkv + (size_t)m * QKVN + col + l * 2;
  float e = (float)p[0], o = (float)p[1];
  float c = cosT[s * 64 + l], sn = sinT[s * 64 + l];
  float e2 = e * c - o * sn;
  float o2 = e * sn + o * c;
  float ss = e2 * e2 + o2 * o2;
#pragma unroll
  for (int off = 32; off > 0; off >>= 1) ss += __shfl_xor(ss, off);
  float r = rsqrtf(ss * (1.0f / 128.0f) + 1e-5f);
  if (isQ) r *= 0.08838834764831845f;  // fold 1/sqrt(HEAD_DIM) into Q
  p[0] = (__bf16)(e2 * r);
  p[1] = (__bf16)(o2 * r);
}

// ---------------- V transpose: qkv V region (b,s,g,d) -> vt (b,g,d,s) ------
__global__ __launch_bounds__(256) void k_transpose_v(const __bf16* __restrict__ qkv,
                                                     __bf16* __restrict__ vt) {
  __shared__ __bf16 tile[64][136];  // padded row, no bank conflicts
  const int t = threadIdx.x;
  const int st = blockIdx.x, bg = blockIdx.y;
  const int b = bg >> 3, g = bg & 7;
  const int s0 = st * 64;
#pragma unroll
  for (int p = 0; p < 4; ++p) {
    int row = p * 16 + (t >> 4);
    int co = (t & 15) * 8;
    *(bf16x8*)&tile[row][co] =
        *(const bf16x8*)&qkv[(size_t)(b * SEQ + s0 + row) * QKVN + 5120 + g * 128 + co];
  }
  __syncthreads();
#pragma unroll
  for (int p = 0; p < 4; ++p) {
    int d = p * 32 + (t >> 3);
    int so = (t & 7) * 8;
    bf16x8 v;
#pragma unroll
    for (int j = 0; j < 8; ++j) v[j] = tile[so + j][d];
    *(bf16x8*)&vt[((size_t)bg * 128 + d) * SEQ + s0 + so] = v;
  }
}

// ---------------- causal flash attention (GQA) ------------------------------
__global__ __launch_bounds__(256) void k_flash(const __bf16* __restrict__ qkv,
                                               const __bf16* __restrict__ vt,
                                               __bf16* __restrict__ attno) {
  __shared__ __bf16 Ks[64 * 128];   // [kv][d], swizzled
  __shared__ __bf16 Vs[128 * 64];   // [d][kv], swizzled
  __shared__ __bf16 Ps[4][16 * 64]; // per-wave [q][kv], swizzled
  const int t = threadIdx.x, w = t >> 6, l = t & 63;
  const int lr = l & 15, lg = l >> 4;
  const int bh = blockIdx.y;        // b*32 + h
  const int b = bh >> 5, h = bh & 31, g = h >> 2;
  const int qt0 = blockIdx.x, qt1 = 31 - (int)blockIdx.x;

  const __bf16* Kb = qkv + 4096 + (size_t)(b * SEQ) * QKVN + g * 128;
  const __bf16* Vtb = vt + ((size_t)(b * 8 + g)) * 128 * SEQ;
  const int wbase = (t & ~63) * 8;
  const int sw = lr & 7;            // read-side XOR (row&7 == lr&7 everywhere)

  for (int pass = 0; pass < 2; ++pass) {
    const int qt = (pass == 0) ? qt0 : qt1;

    const __bf16* Qb = qkv + (size_t)(b * SEQ + qt * 64 + w * 16 + lr) * QKVN + h * 128;
    bf16x8 qf[4];
#pragma unroll
    for (int kk = 0; kk < 4; ++kk) qf[kk] = *(const bf16x8*)&Qb[kk * 32 + lg * 8];

    f32x4 oacc[8] = {};
    float mrow[4], lsum[4];
#pragma unroll
    for (int r = 0; r < 4; ++r) { mrow[r] = -1e30f; lsum[r] = 0.f; }

    for (int kt = 0; kt <= qt; ++kt) {
      const int kv0 = kt * 64;
#pragma unroll
      for (int i = 0; i < 4; ++i) {
        int e = i * 256 + t;
        gld_lds16(Kb + (size_t)(kv0 + (e >> 4)) * QKVN + ((e & 15) ^ ((e >> 4) & 7)) * 8,
                  &Ks[i * 2048 + wbase]);
      }
#pragma unroll
      for (int i = 0; i < 4; ++i) {
        int e = i * 256 + t;
        gld_lds16(Vtb + (size_t)(e >> 3) * SEQ + kv0 + (((e & 7) ^ ((e >> 3) & 7))) * 8,
                  &Vs[i * 2048 + wbase]);
      }
      __syncthreads();

      // S = Q K^T
      f32x4 sc[4] = {};
#pragma unroll
      for (int kk = 0; kk < 4; ++kk)
#pragma unroll
        for (int n = 0; n < 4; ++n) {
          bf16x8 kf = *(const bf16x8*)&Ks[(n * 16 + lr) * 128 + ((kk * 4 + lg) ^ sw) * 8];
          sc[n] = __builtin_amdgcn_mfma_f32_16x16x32_bf16(qf[kk], kf, sc[n], 0, 0, 0);
        }

      if (kt == qt) {  // diagonal tile: causal mask
#pragma unroll
        for (int n = 0; n < 4; ++n)
#pragma unroll
          for (int r = 0; r < 4; ++r)
            if (n * 16 + lr > w * 16 + lg * 4 + r) sc[n][r] = -1e30f;
      }

      // online softmax (row = lg*4 + r; 16 lanes hold the cols)
#pragma unroll
      for (int r = 0; r < 4; ++r) {
        float pm = fmaxf(fmaxf(sc[0][r], sc[1][r]), fmaxf(sc[2][r], sc[3][r]));
#pragma unroll
        for (int off = 8; off > 0; off >>= 1) pm = fmaxf(pm, __shfl_xor(pm, off));
        float mn = fmaxf(mrow[r], pm);
        float corr = __expf(mrow[r] - mn);
        mrow[r] = mn;
        float ps = 0.f;
#pragma unroll
        for (int n = 0; n < 4; ++n) { sc[n][r] = __expf(sc[n][r] - mn); ps += sc[n][r]; }
#pragma unroll
        for (int off = 8; off > 0; off >>= 1) ps += __shfl_xor(ps, off);
        lsum[r] = lsum[r] * corr + ps;
#pragma unroll
        for (int dn = 0; dn < 8; ++dn) oacc[dn][r] *= corr;
      }

      // P -> LDS (swizzled)
#pragma unroll
      for (int n = 0; n < 4; ++n)
#pragma unroll
        for (int r = 0; r < 4; ++r) {
          int row = lg * 4 + r;
          Ps[w][row * 64 + (((n * 2 + (lr >> 3)) ^ (row & 7)) * 8) + (lr & 7)] = (__bf16)sc[n][r];
        }

      // O += P V
#pragma unroll
      for (int ks = 0; ks < 2; ++ks) {
        bf16x8 pf = *(const bf16x8*)&Ps[w][lr * 64 + ((ks * 4 + lg) ^ sw) * 8];
#pragma unroll
        for (int dn = 0; dn < 8; ++dn) {
          bf16x8 vf = *(const bf16x8*)&Vs[(dn * 16 + lr) * 64 + ((ks * 4 + lg) ^ sw) * 8];
          oacc[dn] = __builtin_amdgcn_mfma_f32_16x16x32_bf16(pf, vf, oacc[dn], 0, 0, 0);
        }
      }
      __syncthreads();
    }

    __bf16* Ob = attno + (size_t)(b * SEQ + qt * 64 + w * 16) * DIMSZ + h * 128;
#pragma unroll
    for (int dn = 0; dn < 8; ++dn)
#pragma unroll
      for (int r = 0; r < 4; ++r)
        Ob[(size_t)(lg * 4 + r) * DIMSZ + dn * 16 + lr] = (__bf16)(oacc[dn][r] / lsum[r]);
  }
}

// ---------------- host launcher --------------------------------------------
extern "C" void kernel_launch(void* const* d_in, const int* in_sizes, int n_in,
                              void* d_out, int out_size, void* d_ws, size_t ws_size,
                              hipStream_t stream) {
  const float* x    = (const float*)d_in[0];
  const float* wq   = (const float*)d_in[1];
  const float* wk   = (const float*)d_in[2];
  const float* wv   = (const float*)d_in[3];
  const float* wo   = (const float*)d_in[4];
  const float* cosT = (const float*)d_in[5];
  const float* sinT = (const float*)d_in[6];
  // d_in[7] (mask) implemented as causal; d_in[8] (start_pos) == 0.

  char* ws = (char*)d_ws;
  __bf16* xb    = (__bf16*)(ws);                    // 4096x4096        (32 MiB)
  __bf16* wqkvb = (__bf16*)(ws + 33554432);         // 6144x4096        (48 MiB)
  __bf16* qkvb  = (__bf16*)(ws + 83886080);         // 4096x6144        (48 MiB)
  __bf16* wob   = (__bf16*)(ws + 134217728);        // 4096x4096        (32 MiB)
  __bf16* vt    = (__bf16*)(ws + 167772160);        // 16x128x2048      ( 8 MiB)
  __bf16* attno = (__bf16*)(ws + 176160768);        // 4096x4096        (32 MiB)
  float* out = (float*)d_out;

  // fp32 -> bf16 conversions (wq/wk/wv concatenated into one 6144x4096 weight)
  k_cvt<<<8192, 256, 0, stream>>>(x, xb, 16777216L);
  k_cvt<<<8192, 256, 0, stream>>>(wq, wqkvb, 16777216L);
  k_cvt<<<2048, 256, 0, stream>>>(wk, wqkvb + 16777216, 4194304L);
  k_cvt<<<2048, 256, 0, stream>>>(wv, wqkvb + 20971520, 4194304L);
  k_cvt<<<8192, 256, 0, stream>>>(wo, wob, 16777216L);

  // QKV projection: M=4096, N=6144 -> 32*24 = 768 blocks (768 % 8 == 0)
  k_gemm256<__bf16><<<768, 512, 0, stream>>>(xb, wqkvb, qkvb, 4096, QKVN, 4096);
  // RoPE + RMSNorm on Q,K (in place), attention scale folded into Q
  k_rope_norm<<<40960, 256, 0, stream>>>(qkvb, cosT, sinT);
  // V -> V^T for contiguous PV operand reads
  k_transpose_v<<<dim3(32, 16), 256, 0, stream>>>(qkvb, vt);
  // causal GQA flash attention (paired q-tiles for balance)
  k_flash<<<dim3(16, 64), 256, 0, stream>>>(qkvb, vt, attno);
  // output projection: M=4096, N=4096 -> 32*16 = 512 blocks
  k_gemm256<float><<<512, 512, 0, stream>>>(attno, wob, out, 4096, DIMSZ, 4096);
}

// Round 4
// 625.857 us; speedup vs baseline: 1.1966x; 1.1966x over previous
//
#include <hip/hip_runtime.h>
#include <hip/hip_bf16.h>
#include <stdint.h>

#define SEQ 2048
#define DIMSZ 4096
#define QKVN 6144   // 4096 Q + 1024 K + 1024 V

typedef __attribute__((ext_vector_type(8))) __bf16 bf16x8;
typedef __attribute__((ext_vector_type(4))) float f32x4;

// async global->LDS, 16B per lane; dest = wave-uniform base + lane*16
static __device__ __forceinline__ void gld_lds16(const void* g, void* l) {
  __builtin_amdgcn_global_load_lds(
      (__attribute__((address_space(1))) void*)(g),
      (__attribute__((address_space(3))) void*)(l), 16, 0, 0);
}

// ---------------- fp32 -> bf16 conversion (vectorized) ----------------
__global__ __launch_bounds__(256) void k_cvt(const float* __restrict__ in,
                                             __bf16* __restrict__ out, long n) {
  long i = (long)blockIdx.x * 256 + threadIdx.x;
  long stride = (long)gridDim.x * 256;
  for (long e = i * 8; e < n; e += stride * 8) {
    float4 v0 = *(const float4*)(in + e);
    float4 v1 = *(const float4*)(in + e + 4);
    bf16x8 o;
    o[0] = (__bf16)v0.x; o[1] = (__bf16)v0.y; o[2] = (__bf16)v0.z; o[3] = (__bf16)v0.w;
    o[4] = (__bf16)v1.x; o[5] = (__bf16)v1.y; o[6] = (__bf16)v1.z; o[7] = (__bf16)v1.w;
    *(bf16x8*)(out + e) = o;
  }
}

// ---------------- bf16 GEMM, C = A * B^T  (A: MxK, B: NxK, both K-contig) --
// 256x256 tile, BK=64, 8 waves (2M x 4N), 128 KiB LDS double-buffer.
// Pipeline: full next-K-tile staged at TOP of phase 0 (8 gld_lds) -> ~3.5
// phases of MFMA cover the HBM latency; single explicit vmcnt(0)+s_barrier
// at the tile boundary. Per-phase raw s_barrier (NO vmcnt drain — that is
// the round-3 mistake __syncthreads would reintroduce).
// T2: 16B-chunk XOR swizzle (chunk ^= row&7) via pre-swizzled global source;
// zero bank conflicts (measured round 3). T5: setprio around each 16-MFMA
// cluster; 4 barrier-separated clusters per K-tile give the role-split.
// Dispatch: plain 2D grid, bn fastest (round-2 order: 231 MB fetch vs 719 MB
// with XCD chunk-swizzle).
template <typename OutT>
__global__ __launch_bounds__(512, 2) void k_gemm256(const __bf16* __restrict__ A,
                                                    const __bf16* __restrict__ B,
                                                    OutT* __restrict__ C,
                                                    int M, int N, int K) {
  __shared__ __bf16 As[2][256 * 64];  // 64 KiB
  __shared__ __bf16 Bs[2][256 * 64];  // 64 KiB
  const int t = threadIdx.x;
  const int l = t & 63;
  const int w = t >> 6;        // 0..7
  const int wm = w >> 2;       // 0..1  (128-row half of the 256-row tile)
  const int wn = w & 3;        // 0..3  (64-col quarter of the 256-col tile)
  const int lr = l & 15, lg = l >> 4;
  const int sw = lr & 7;       // read-side chunk XOR (row&7 == lr&7 for all frags)
  const int bm = blockIdx.y, bn = blockIdx.x;

  const __bf16* Ab = A + (size_t)bm * 256 * K;
  const __bf16* Bb = B + (size_t)bn * 256 * K;

  // staging geometry: one gld_lds issue = 512 thr x 16B = 64 rows x 64 cols
  const int srow = t >> 3;                        // row within issue
  const int scol = ((t & 7) ^ (srow & 7)) << 3;   // pre-swizzled source col
  const int ldst = (t & ~63) * 8;                 // wave-uniform LDS elem base
  const __bf16* Asrc = Ab + (size_t)srow * K + scol;
  const __bf16* Bsrc = Bb + (size_t)srow * K + scol;

#define STAGE_TILE(buf, kt)                                             \
  do {                                                                  \
    _Pragma("unroll") for (int i_ = 0; i_ < 4; ++i_)                    \
        gld_lds16(Asrc + (size_t)(i_ * 64) * K + (kt), &As[buf][i_ * 4096 + ldst]); \
    _Pragma("unroll") for (int i_ = 0; i_ < 4; ++i_)                    \
        gld_lds16(Bsrc + (size_t)(i_ * 64) * K + (kt), &Bs[buf][i_ * 4096 + ldst]); \
  } while (0)

  f32x4 acc[8][4] = {};
  bf16x8 a[4][2], b[2][2];

  const int nt = K >> 6;

  // prologue: stage tile 0 into buf 0; full drain + barrier
  STAGE_TILE(0, 0);
  __syncthreads();

  for (int tI = 0; tI < nt; ++tI) {
    const int cur = tI & 1;

    // ---- phase 0: frags a(mi0-3), b(ni0-1); stage next tile; MFMA q0 ----
#pragma unroll
    for (int mi = 0; mi < 4; ++mi)
#pragma unroll
      for (int kk = 0; kk < 2; ++kk)
        a[mi][kk] = *(const bf16x8*)&As[cur][(wm * 128 + mi * 16 + lr) * 64 + (((kk * 4 + lg) ^ sw) * 8)];
#pragma unroll
    for (int ni = 0; ni < 2; ++ni)
#pragma unroll
      for (int kk = 0; kk < 2; ++kk)
        b[ni][kk] = *(const bf16x8*)&Bs[cur][(wn * 64 + ni * 16 + lr) * 64 + (((kk * 4 + lg) ^ sw) * 8)];
    if (tI + 1 < nt) STAGE_TILE(cur ^ 1, (size_t)(tI + 1) * 64);
    __builtin_amdgcn_s_barrier();
    __builtin_amdgcn_s_setprio(1);
#pragma unroll
    for (int mi = 0; mi < 4; ++mi)
#pragma unroll
      for (int ni = 0; ni < 2; ++ni)
#pragma unroll
        for (int kk = 0; kk < 2; ++kk)
          acc[mi][ni] = __builtin_amdgcn_mfma_f32_16x16x32_bf16(a[mi][kk], b[ni][kk], acc[mi][ni], 0, 0, 0);
    __builtin_amdgcn_s_setprio(0);

    // ---- phase 1: frags b(ni2-3); MFMA q1 = (mi0-3 x ni2-3) ----
#pragma unroll
    for (int ni = 0; ni < 2; ++ni)
#pragma unroll
      for (int kk = 0; kk < 2; ++kk)
        b[ni][kk] = *(const bf16x8*)&Bs[cur][(wn * 64 + (ni + 2) * 16 + lr) * 64 + (((kk * 4 + lg) ^ sw) * 8)];
    __builtin_amdgcn_s_barrier();
    __builtin_amdgcn_s_setprio(1);
#pragma unroll
    for (int mi = 0; mi < 4; ++mi)
#pragma unroll
      for (int ni = 0; ni < 2; ++ni)
#pragma unroll
        for (int kk = 0; kk < 2; ++kk)
          acc[mi][ni + 2] = __builtin_amdgcn_mfma_f32_16x16x32_bf16(a[mi][kk], b[ni][kk], acc[mi][ni + 2], 0, 0, 0);
    __builtin_amdgcn_s_setprio(0);

    // ---- phase 2: frags a(mi4-7); MFMA q2 = (mi4-7 x ni2-3) ----
#pragma unroll
    for (int mi = 0; mi < 4; ++mi)
#pragma unroll
      for (int kk = 0; kk < 2; ++kk)
        a[mi][kk] = *(const bf16x8*)&As[cur][(wm * 128 + (mi + 4) * 16 + lr) * 64 + (((kk * 4 + lg) ^ sw) * 8)];
    __builtin_amdgcn_s_barrier();
    __builtin_amdgcn_s_setprio(1);
#pragma unroll
    for (int mi = 0; mi < 4; ++mi)
#pragma unroll
      for (int ni = 0; ni < 2; ++ni)
#pragma unroll
        for (int kk = 0; kk < 2; ++kk)
          acc[mi + 4][ni + 2] = __builtin_amdgcn_mfma_f32_16x16x32_bf16(a[mi][kk], b[ni][kk], acc[mi + 4][ni + 2], 0, 0, 0);
    __builtin_amdgcn_s_setprio(0);

    // ---- phase 3: frags b(ni0-1) again; MFMA q3 = (mi4-7 x ni0-1) ----
#pragma unroll
    for (int ni = 0; ni < 2; ++ni)
#pragma unroll
      for (int kk = 0; kk < 2; ++kk)
        b[ni][kk] = *(const bf16x8*)&Bs[cur][(wn * 64 + ni * 16 + lr) * 64 + (((kk * 4 + lg) ^ sw) * 8)];
    __builtin_amdgcn_s_barrier();
    __builtin_amdgcn_s_setprio(1);
#pragma unroll
    for (int mi = 0; mi < 4; ++mi)
#pragma unroll
      for (int ni = 0; ni < 2; ++ni)
#pragma unroll
        for (int kk = 0; kk < 2; ++kk)
          acc[mi + 4][ni] = __builtin_amdgcn_mfma_f32_16x16x32_bf16(a[mi][kk], b[ni][kk], acc[mi + 4][ni], 0, 0, 0);
    __builtin_amdgcn_s_setprio(0);

    // ---- tile boundary: staged loads had phases 0-3 to land ----
    asm volatile("s_waitcnt vmcnt(0)" ::: "memory");
    __builtin_amdgcn_sched_barrier(0);
    __builtin_amdgcn_s_barrier();
  }
#undef STAGE_TILE

  const int row0 = bm * 256 + wm * 128;
  const int col0 = bn * 256 + wn * 64;
#pragma unroll
  for (int mi = 0; mi < 8; ++mi)
#pragma unroll
    for (int ni = 0; ni < 4; ++ni)
#pragma unroll
      for (int r = 0; r < 4; ++r)
        C[(size_t)(row0 + mi * 16 + lg * 4 + r) * N + (col0 + ni * 16 + lr)] =
            (OutT)acc[mi][ni][r];
}

// ---------------- fused RoPE + RMSNorm (in-place on Q and K regions) -------
__global__ __launch_bounds__(256) void k_rope_norm(__bf16* __restrict__ qkv,
                                                   const float* __restrict__ cosT,
                                                   const float* __restrict__ sinT) {
  const int task = blockIdx.x * 4 + (threadIdx.x >> 6);
  const int l = threadIdx.x & 63;
  const int m = task / 40;          // row in [0, 4096)
  const int h = task - m * 40;      // 0..31 = Q heads, 32..39 = K heads
  const int s = m & (SEQ - 1);
  const bool isQ = h < 32;
  const int col = isQ ? h * 128 : 4096 + (h - 32) * 128;
  __bf16* p = qkv + (size_t)m * QKVN + col + l * 2;
  float e = (float)p[0], o = (float)p[1];
  float c = cosT[s * 64 + l], sn = sinT[s * 64 + l];
  float e2 = e * c - o * sn;
  float o2 = e * sn + o * c;
  float ss = e2 * e2 + o2 * o2;
#pragma unroll
  for (int off = 32; off > 0; off >>= 1) ss += __shfl_xor(ss, off);
  float r = rsqrtf(ss * (1.0f / 128.0f) + 1e-5f);
  if (isQ) r *= 0.08838834764831845f;  // fold 1/sqrt(HEAD_DIM) into Q
  p[0] = (__bf16)(e2 * r);
  p[1] = (__bf16)(o2 * r);
}

// ---------------- V transpose: qkv V region (b,s,g,d) -> vt (b,g,d,s) ------
__global__ __launch_bounds__(256) void k_transpose_v(const __bf16* __restrict__ qkv,
                                                     __bf16* __restrict__ vt) {
  __shared__ __bf16 tile[64][136];  // padded row, no bank conflicts
  const int t = threadIdx.x;
  const int st = blockIdx.x, bg = blockIdx.y;
  const int b = bg >> 3, g = bg & 7;
  const int s0 = st * 64;
#pragma unroll
  for (int p = 0; p < 4; ++p) {
    int row = p * 16 + (t >> 4);
    int co = (t & 15) * 8;
    *(bf16x8*)&tile[row][co] =
        *(const bf16x8*)&qkv[(size_t)(b * SEQ + s0 + row) * QKVN + 5120 + g * 128 + co];
  }
  __syncthreads();
#pragma unroll
  for (int p = 0; p < 4; ++p) {
    int d = p * 32 + (t >> 3);
    int so = (t & 7) * 8;
    bf16x8 v;
#pragma unroll
    for (int j = 0; j < 8; ++j) v[j] = tile[so + j][d];
    *(bf16x8*)&vt[((size_t)bg * 128 + d) * SEQ + s0 + so] = v;
  }
}

// ---------------- causal flash attention (GQA) ------------------------------
__global__ __launch_bounds__(256) void k_flash(const __bf16* __restrict__ qkv,
                                               const __bf16* __restrict__ vt,
                                               __bf16* __restrict__ attno) {
  __shared__ __bf16 Ks[64 * 128];   // [kv][d], swizzled
  __shared__ __bf16 Vs[128 * 64];   // [d][kv], swizzled
  __shared__ __bf16 Ps[4][16 * 64]; // per-wave [q][kv], swizzled
  const int t = threadIdx.x, w = t >> 6, l = t & 63;
  const int lr = l & 15, lg = l >> 4;
  const int bh = blockIdx.y;        // b*32 + h
  const int b = bh >> 5, h = bh & 31, g = h >> 2;
  const int qt0 = blockIdx.x, qt1 = 31 - (int)blockIdx.x;

  const __bf16* Kb = qkv + 4096 + (size_t)(b * SEQ) * QKVN + g * 128;
  const __bf16* Vtb = vt + ((size_t)(b * 8 + g)) * 128 * SEQ;
  const int wbase = (t & ~63) * 8;
  const int sw = lr & 7;            // read-side XOR (row&7 == lr&7 everywhere)

  for (int pass = 0; pass < 2; ++pass) {
    const int qt = (pass == 0) ? qt0 : qt1;

    const __bf16* Qb = qkv + (size_t)(b * SEQ + qt * 64 + w * 16 + lr) * QKVN + h * 128;
    bf16x8 qf[4];
#pragma unroll
    for (int kk = 0; kk < 4; ++kk) qf[kk] = *(const bf16x8*)&Qb[kk * 32 + lg * 8];

    f32x4 oacc[8] = {};
    float mrow[4], lsum[4];
#pragma unroll
    for (int r = 0; r < 4; ++r) { mrow[r] = -1e30f; lsum[r] = 0.f; }

    for (int kt = 0; kt <= qt; ++kt) {
      const int kv0 = kt * 64;
#pragma unroll
      for (int i = 0; i < 4; ++i) {
        int e = i * 256 + t;
        gld_lds16(Kb + (size_t)(kv0 + (e >> 4)) * QKVN + ((e & 15) ^ ((e >> 4) & 7)) * 8,
                  &Ks[i * 2048 + wbase]);
      }
#pragma unroll
      for (int i = 0; i < 4; ++i) {
        int e = i * 256 + t;
        gld_lds16(Vtb + (size_t)(e >> 3) * SEQ + kv0 + (((e & 7) ^ ((e >> 3) & 7))) * 8,
                  &Vs[i * 2048 + wbase]);
      }
      __syncthreads();

      // S = Q K^T
      f32x4 sc[4] = {};
#pragma unroll
      for (int kk = 0; kk < 4; ++kk)
#pragma unroll
        for (int n = 0; n < 4; ++n) {
          bf16x8 kf = *(const bf16x8*)&Ks[(n * 16 + lr) * 128 + ((kk * 4 + lg) ^ sw) * 8];
          sc[n] = __builtin_amdgcn_mfma_f32_16x16x32_bf16(qf[kk], kf, sc[n], 0, 0, 0);
        }

      if (kt == qt) {  // diagonal tile: causal mask
#pragma unroll
        for (int n = 0; n < 4; ++n)
#pragma unroll
          for (int r = 0; r < 4; ++r)
            if (n * 16 + lr > w * 16 + lg * 4 + r) sc[n][r] = -1e30f;
      }

      // online softmax (row = lg*4 + r; 16 lanes hold the cols)
#pragma unroll
      for (int r = 0; r < 4; ++r) {
        float pm = fmaxf(fmaxf(sc[0][r], sc[1][r]), fmaxf(sc[2][r], sc[3][r]));
#pragma unroll
        for (int off = 8; off > 0; off >>= 1) pm = fmaxf(pm, __shfl_xor(pm, off));
        float mn = fmaxf(mrow[r], pm);
        float corr = __expf(mrow[r] - mn);
        mrow[r] = mn;
        float ps = 0.f;
#pragma unroll
        for (int n = 0; n < 4; ++n) { sc[n][r] = __expf(sc[n][r] - mn); ps += sc[n][r]; }
#pragma unroll
        for (int off = 8; off > 0; off >>= 1) ps += __shfl_xor(ps, off);
        lsum[r] = lsum[r] * corr + ps;
#pragma unroll
        for (int dn = 0; dn < 8; ++dn) oacc[dn][r] *= corr;
      }

      // P -> LDS (swizzled)
#pragma unroll
      for (int n = 0; n < 4; ++n)
#pragma unroll
        for (int r = 0; r < 4; ++r) {
          int row = lg * 4 + r;
          Ps[w][row * 64 + (((n * 2 + (lr >> 3)) ^ (row & 7)) * 8) + (lr & 7)] = (__bf16)sc[n][r];
        }

      // O += P V
#pragma unroll
      for (int ks = 0; ks < 2; ++ks) {
        bf16x8 pf = *(const bf16x8*)&Ps[w][lr * 64 + ((ks * 4 + lg) ^ sw) * 8];
#pragma unroll
        for (int dn = 0; dn < 8; ++dn) {
          bf16x8 vf = *(const bf16x8*)&Vs[(dn * 16 + lr) * 64 + ((ks * 4 + lg) ^ sw) * 8];
          oacc[dn] = __builtin_amdgcn_mfma_f32_16x16x32_bf16(pf, vf, oacc[dn], 0, 0, 0);
        }
      }
      __syncthreads();
    }

    __bf16* Ob = attno + (size_t)(b * SEQ + qt * 64 + w * 16) * DIMSZ + h * 128;
#pragma unroll
    for (int dn = 0; dn < 8; ++dn)
#pragma unroll
      for (int r = 0; r < 4; ++r)
        Ob[(size_t)(lg * 4 + r) * DIMSZ + dn * 16 + lr] = (__bf16)(oacc[dn][r] / lsum[r]);
  }
}

// ---------------- host launcher --------------------------------------------
extern "C" void kernel_launch(void* const* d_in, const int* in_sizes, int n_in,
                              void* d_out, int out_size, void* d_ws, size_t ws_size,
                              hipStream_t stream) {
  const float* x    = (const float*)d_in[0];
  const float* wq   = (const float*)d_in[1];
  const float* wk   = (const float*)d_in[2];
  const float* wv   = (const float*)d_in[3];
  const float* wo   = (const float*)d_in[4];
  const float* cosT = (const float*)d_in[5];
  const float* sinT = (const float*)d_in[6];
  // d_in[7] (mask) implemented as causal; d_in[8] (start_pos) == 0.

  char* ws = (char*)d_ws;
  __bf16* xb    = (__bf16*)(ws);                    // 4096x4096        (32 MiB)
  __bf16* wqkvb = (__bf16*)(ws + 33554432);         // 6144x4096        (48 MiB)
  __bf16* qkvb  = (__bf16*)(ws + 83886080);         // 4096x6144        (48 MiB)
  __bf16* wob   = (__bf16*)(ws + 134217728);        // 4096x4096        (32 MiB)
  __bf16* vt    = (__bf16*)(ws + 167772160);        // 16x128x2048      ( 8 MiB)
  __bf16* attno = (__bf16*)(ws + 176160768);        // 4096x4096        (32 MiB)
  float* out = (float*)d_out;

  // fp32 -> bf16 conversions (wq/wk/wv concatenated into one 6144x4096 weight)
  k_cvt<<<8192, 256, 0, stream>>>(x, xb, 16777216L);
  k_cvt<<<8192, 256, 0, stream>>>(wq, wqkvb, 16777216L);
  k_cvt<<<2048, 256, 0, stream>>>(wk, wqkvb + 16777216, 4194304L);
  k_cvt<<<2048, 256, 0, stream>>>(wv, wqkvb + 20971520, 4194304L);
  k_cvt<<<8192, 256, 0, stream>>>(wo, wob, 16777216L);

  // QKV projection: M=4096, N=6144 -> grid (24, 16), bn fastest
  k_gemm256<__bf16><<<dim3(24, 16), 512, 0, stream>>>(xb, wqkvb, qkvb, 4096, QKVN, 4096);
  // RoPE + RMSNorm on Q,K (in place), attention scale folded into Q
  k_rope_norm<<<40960, 256, 0, stream>>>(qkvb, cosT, sinT);
  // V -> V^T for contiguous PV operand reads
  k_transpose_v<<<dim3(32, 16), 256, 0, stream>>>(qkvb, vt);
  // causal GQA flash attention (paired q-tiles for balance)
  k_flash<<<dim3(16, 64), 256, 0, stream>>>(qkvb, vt, attno);
  // output projection: M=4096, N=4096 -> grid (16, 16)
  k_gemm256<float><<<dim3(16, 16), 512, 0, stream>>>(attno, wob, out, 4096, DIMSZ, 4096);
}